// Round 1
// baseline (4126.422 us; speedup 1.0000x reference)
//
#include <hip/hip_runtime.h>
#include <math.h>

#define B_   64
#define NPB  3468            // points (visual words) per batch
#define NPTS (B_ * NPB)      // 221952
#define KC   248
#define D_   64
#define NV   (KC * D_)       // 15872 per-batch vlad elements

// ---------------------------------------------------------------- zero d_out
__global__ __launch_bounds__(256) void zero_kernel(float4* __restrict__ out, int n4) {
    int i = blockIdx.x * 256 + threadIdx.x;
    if (i < n4) out[i] = make_float4(0.f, 0.f, 0.f, 0.f);
}

// ------------------------------------------- per-(b,d) inv-norms + code half-norms
// blocks 0..63: inv_norm[b*64+d] = 1/max(||vw[b,:,d]||, 1e-12)
// block 64:     hn[k] = 0.5*||codes[k]||^2
__global__ __launch_bounds__(256) void norms_kernel(const float* __restrict__ feat,
                                                    const float* __restrict__ codes,
                                                    float* __restrict__ inv_norm,
                                                    float* __restrict__ hn) {
    if (blockIdx.x == B_) {
        int k = threadIdx.x;
        if (k < KC) {
            float s = 0.f;
            #pragma unroll 8
            for (int d = 0; d < D_; ++d) { float c = codes[k * D_ + d]; s += c * c; }
            hn[k] = 0.5f * s;
        }
        return;
    }
    int b = blockIdx.x, t = threadIdx.x;
    const float4* f = (const float4*)(feat + (size_t)b * (NPB * D_));
    const int N4 = NPB * D_ / 4;   // 55488 float4s per batch
    float ax = 0.f, ay = 0.f, az = 0.f, aw = 0.f;
    for (int j = 0; j < (N4 + 255) / 256; ++j) {
        int i4 = t + j * 256;
        if (i4 < N4) {
            float4 a = f[i4];
            ax += a.x * a.x; ay += a.y * a.y; az += a.z * a.z; aw += a.w * a.w;
        }
    }
    // thread t's float4 always covers dims 4*(t&15)..4*(t&15)+3 (256 % 64 == 0)
    __shared__ float4 red[256];
    red[t] = make_float4(ax, ay, az, aw);
    __syncthreads();
    if (t < 16) {
        float sx = 0.f, sy = 0.f, sz = 0.f, sw = 0.f;
        #pragma unroll
        for (int j = 0; j < 16; ++j) {
            float4 a = red[t + 16 * j];
            sx += a.x; sy += a.y; sz += a.z; sw += a.w;
        }
        float* dst = inv_norm + b * D_ + 4 * t;
        dst[0] = 1.f / fmaxf(sqrtf(sx), 1e-12f);
        dst[1] = 1.f / fmaxf(sqrtf(sy), 1e-12f);
        dst[2] = 1.f / fmaxf(sqrtf(sz), 1e-12f);
        dst[3] = 1.f / fmaxf(sqrtf(sw), 1e-12f);
    }
}

// ------------------------------------------- assignment + residual scatter-add
// 2 points per thread: amortizes LDS code reads (16 b128 reads vs 128 FMAs per k)
__global__ __launch_bounds__(256) void assign_kernel(const float* __restrict__ feat,
                                                     const float* __restrict__ codes,
                                                     const float* __restrict__ inv_norm,
                                                     const float* __restrict__ hn,
                                                     float* __restrict__ vlad) {
    __shared__ float4 lc[KC * 16];   // 63488 B
    __shared__ float  lhn[KC];       //   992 B
    int t = threadIdx.x;
    const float4* c4 = (const float4*)codes;
    for (int i = t; i < KC * 16; i += 256) lc[i] = c4[i];
    for (int i = t; i < KC; i += 256) lhn[i] = hn[i];
    __syncthreads();

    int base = blockIdx.x * 512;
    int p0 = base + t;
    int p1 = base + 256 + t;
    bool w1 = (p1 < NPTS);
    int p1c = w1 ? p1 : p0;

    int b0 = p0 / NPB;
    int b1 = p1c / NPB;

    float v0[D_], v1[D_];
    {
        const float4* f0 = (const float4*)(feat + (size_t)p0 * D_);
        const float4* n0 = (const float4*)(inv_norm + b0 * D_);
        #pragma unroll
        for (int j = 0; j < 16; ++j) {
            float4 a = f0[j], w = n0[j];
            v0[4*j+0] = a.x * w.x; v0[4*j+1] = a.y * w.y;
            v0[4*j+2] = a.z * w.z; v0[4*j+3] = a.w * w.w;
        }
        const float4* f1 = (const float4*)(feat + (size_t)p1c * D_);
        const float4* n1 = (const float4*)(inv_norm + b1 * D_);
        #pragma unroll
        for (int j = 0; j < 16; ++j) {
            float4 a = f1[j], w = n1[j];
            v1[4*j+0] = a.x * w.x; v1[4*j+1] = a.y * w.y;
            v1[4*j+2] = a.z * w.z; v1[4*j+3] = a.w * w.w;
        }
    }

    float best0 = -3.0e38f, best1 = -3.0e38f;
    int k0 = 0, k1 = 0;
    for (int k = 0; k < KC; ++k) {
        float a0 = 0.f, a1 = 0.f, a2 = 0.f, a3 = 0.f;
        float c0 = 0.f, c1 = 0.f, c2 = 0.f, c3 = 0.f;
        #pragma unroll
        for (int j = 0; j < 16; ++j) {
            float4 c = lc[k * 16 + j];
            a0 += v0[4*j+0] * c.x; a1 += v0[4*j+1] * c.y;
            a2 += v0[4*j+2] * c.z; a3 += v0[4*j+3] * c.w;
            c0 += v1[4*j+0] * c.x; c1 += v1[4*j+1] * c.y;
            c2 += v1[4*j+2] * c.z; c3 += v1[4*j+3] * c.w;
        }
        float s0 = (a0 + a1) + (a2 + a3) - lhn[k];
        float s1 = (c0 + c1) + (c2 + c3) - lhn[k];
        if (s0 > best0) { best0 = s0; k0 = k; }
        if (s1 > best1) { best1 = s1; k1 = k; }
    }

    // residual for point 0 (overwrite v0 in place to save VGPRs)
    {
        float ss = 0.f;
        #pragma unroll
        for (int j = 0; j < 16; ++j) {
            float4 c = lc[k0 * 16 + j];
            v0[4*j+0] -= c.x; v0[4*j+1] -= c.y; v0[4*j+2] -= c.z; v0[4*j+3] -= c.w;
            ss += v0[4*j+0]*v0[4*j+0] + v0[4*j+1]*v0[4*j+1]
                + v0[4*j+2]*v0[4*j+2] + v0[4*j+3]*v0[4*j+3];
        }
        float rinv = 1.f / (sqrtf(ss) + 1e-8f);
        float* dst = vlad + ((size_t)b0 * KC + k0) * D_;
        #pragma unroll
        for (int d = 0; d < D_; ++d) atomicAdd(dst + d, v0[d] * rinv);
    }
    if (w1) {
        float ss = 0.f;
        #pragma unroll
        for (int j = 0; j < 16; ++j) {
            float4 c = lc[k1 * 16 + j];
            v1[4*j+0] -= c.x; v1[4*j+1] -= c.y; v1[4*j+2] -= c.z; v1[4*j+3] -= c.w;
            ss += v1[4*j+0]*v1[4*j+0] + v1[4*j+1]*v1[4*j+1]
                + v1[4*j+2]*v1[4*j+2] + v1[4*j+3]*v1[4*j+3];
        }
        float rinv = 1.f / (sqrtf(ss) + 1e-8f);
        float* dst = vlad + ((size_t)b1 * KC + k1) * D_;
        #pragma unroll
        for (int d = 0; d < D_; ++d) atomicAdd(dst + d, v1[d] * rinv);
    }
}

// ------------------------------------------- per-batch standardize, in place
__global__ __launch_bounds__(256) void std_kernel(float* __restrict__ v) {
    int b = blockIdx.x, t = threadIdx.x;
    float* row = v + (size_t)b * NV;
    double s = 0.0, ss = 0.0;
    for (int i = t; i < NV; i += 256) {
        float x = row[i];
        s += (double)x;
        ss += (double)x * (double)x;
    }
    __shared__ double rs[256], rss[256];
    rs[t] = s; rss[t] = ss;
    __syncthreads();
    for (int off = 128; off > 0; off >>= 1) {
        if (t < off) { rs[t] += rs[t + off]; rss[t] += rss[t + off]; }
        __syncthreads();
    }
    __shared__ float fmean, fscale;
    if (t == 0) {
        double S = rs[0], SS = rss[0];
        double mean = S / (double)NV;
        double var = (SS - S * S / (double)NV) / (double)(NV - 1);
        double sd = sqrt(var > 0.0 ? var : 0.0);
        fmean = (float)mean;
        fscale = (float)(1.0 / (sd + 1e-8));
    }
    __syncthreads();
    float m = fmean, sc = fscale;
    for (int i = t; i < NV; i += 256) row[i] = (row[i] - m) * sc;
}

extern "C" void kernel_launch(void* const* d_in, const int* in_sizes, int n_in,
                              void* d_out, int out_size, void* d_ws, size_t ws_size,
                              hipStream_t stream) {
    const float* feat  = (const float*)d_in[0];
    const float* codes = (const float*)d_in[1];
    float* out = (float*)d_out;

    float* inv_norm = (float*)d_ws;            // 4096 floats
    float* hn = inv_norm + B_ * D_;            // 248 floats

    const int n4 = (B_ * NV) / 4;              // 253952 float4s in d_out
    hipLaunchKernelGGL(zero_kernel, dim3((n4 + 255) / 256), dim3(256), 0, stream,
                       (float4*)out, n4);
    hipLaunchKernelGGL(norms_kernel, dim3(B_ + 1), dim3(256), 0, stream,
                       feat, codes, inv_norm, hn);
    hipLaunchKernelGGL(assign_kernel, dim3((NPTS + 511) / 512), dim3(256), 0, stream,
                       feat, codes, inv_norm, hn, out);
    hipLaunchKernelGGL(std_kernel, dim3(B_), dim3(256), 0, stream, out);
}

// Round 2
// 557.424 us; speedup vs baseline: 7.4027x; 7.4027x over previous
//
#include <hip/hip_runtime.h>
#include <math.h>

#define B_   64
#define NPB  3468            // points (visual words) per batch
#define NPTS (B_ * NPB)      // 221952
#define KC   248
#define D_   64
#define NV   (KC * D_)       // 15872 per-batch vlad elements

// ------------------------------------------- per-(b,d) inv-norms + code half-norms
// blocks 0..63: inv_norm[b*64+d] = 1/max(||vw[b,:,d]||, 1e-12)
// block 64:     hn[k] = 0.5*||codes[k]||^2
__global__ __launch_bounds__(256) void norms_kernel(const float* __restrict__ feat,
                                                    const float* __restrict__ codes,
                                                    float* __restrict__ inv_norm,
                                                    float* __restrict__ hn) {
    if (blockIdx.x == B_) {
        int k = threadIdx.x;
        if (k < KC) {
            float s = 0.f;
            #pragma unroll 8
            for (int d = 0; d < D_; ++d) { float c = codes[k * D_ + d]; s += c * c; }
            hn[k] = 0.5f * s;
        }
        return;
    }
    int b = blockIdx.x, t = threadIdx.x;
    const float4* f = (const float4*)(feat + (size_t)b * (NPB * D_));
    const int N4 = NPB * D_ / 4;   // 55488 float4s per batch
    float ax = 0.f, ay = 0.f, az = 0.f, aw = 0.f;
    for (int j = 0; j < (N4 + 255) / 256; ++j) {
        int i4 = t + j * 256;
        if (i4 < N4) {
            float4 a = f[i4];
            ax += a.x * a.x; ay += a.y * a.y; az += a.z * a.z; aw += a.w * a.w;
        }
    }
    // thread t's float4 always covers dims 4*(t&15)..4*(t&15)+3 (256 % 64 == 0)
    __shared__ float4 red[256];
    red[t] = make_float4(ax, ay, az, aw);
    __syncthreads();
    if (t < 16) {
        float sx = 0.f, sy = 0.f, sz = 0.f, sw = 0.f;
        #pragma unroll
        for (int j = 0; j < 16; ++j) {
            float4 a = red[t + 16 * j];
            sx += a.x; sy += a.y; sz += a.z; sw += a.w;
        }
        float* dst = inv_norm + b * D_ + 4 * t;
        dst[0] = 1.f / fmaxf(sqrtf(sx), 1e-12f);
        dst[1] = 1.f / fmaxf(sqrtf(sy), 1e-12f);
        dst[2] = 1.f / fmaxf(sqrtf(sz), 1e-12f);
        dst[3] = 1.f / fmaxf(sqrtf(sw), 1e-12f);
    }
}

// ------------------------------------------- assignment: per-point best code + rinv
// 2 points per thread. ||r||^2 = ||vw||^2 - 2*best  (best = vw.c - 0.5||c||^2)
__global__ __launch_bounds__(256) void assign_kernel(const float* __restrict__ feat,
                                                     const float* __restrict__ codes,
                                                     const float* __restrict__ inv_norm,
                                                     const float* __restrict__ hn,
                                                     unsigned char* __restrict__ kout,
                                                     float* __restrict__ rinvout) {
    __shared__ float4 lc[KC * 16];   // 63488 B
    __shared__ float  lhn[KC];
    int t = threadIdx.x;
    const float4* c4 = (const float4*)codes;
    for (int i = t; i < KC * 16; i += 256) lc[i] = c4[i];
    for (int i = t; i < KC; i += 256) lhn[i] = hn[i];
    __syncthreads();

    int base = blockIdx.x * 512;
    int p0 = base + t;
    int p1 = base + 256 + t;
    bool w1 = (p1 < NPTS);
    int p1c = w1 ? p1 : p0;

    int b0 = p0 / NPB;
    int b1 = p1c / NPB;

    float v0[D_], v1[D_];
    float q0 = 0.f, q1 = 0.f;
    {
        const float4* f0 = (const float4*)(feat + (size_t)p0 * D_);
        const float4* n0 = (const float4*)(inv_norm + b0 * D_);
        #pragma unroll
        for (int j = 0; j < 16; ++j) {
            float4 a = f0[j], w = n0[j];
            v0[4*j+0] = a.x * w.x; v0[4*j+1] = a.y * w.y;
            v0[4*j+2] = a.z * w.z; v0[4*j+3] = a.w * w.w;
            q0 += v0[4*j+0]*v0[4*j+0] + v0[4*j+1]*v0[4*j+1]
                + v0[4*j+2]*v0[4*j+2] + v0[4*j+3]*v0[4*j+3];
        }
        const float4* f1 = (const float4*)(feat + (size_t)p1c * D_);
        const float4* n1 = (const float4*)(inv_norm + b1 * D_);
        #pragma unroll
        for (int j = 0; j < 16; ++j) {
            float4 a = f1[j], w = n1[j];
            v1[4*j+0] = a.x * w.x; v1[4*j+1] = a.y * w.y;
            v1[4*j+2] = a.z * w.z; v1[4*j+3] = a.w * w.w;
            q1 += v1[4*j+0]*v1[4*j+0] + v1[4*j+1]*v1[4*j+1]
                + v1[4*j+2]*v1[4*j+2] + v1[4*j+3]*v1[4*j+3];
        }
    }

    float best0 = -3.0e38f, best1 = -3.0e38f;
    int k0 = 0, k1 = 0;
    for (int k = 0; k < KC; ++k) {
        float a0 = 0.f, a1 = 0.f, a2 = 0.f, a3 = 0.f;
        float c0 = 0.f, c1 = 0.f, c2 = 0.f, c3 = 0.f;
        #pragma unroll
        for (int j = 0; j < 16; ++j) {
            float4 c = lc[k * 16 + j];
            a0 += v0[4*j+0] * c.x; a1 += v0[4*j+1] * c.y;
            a2 += v0[4*j+2] * c.z; a3 += v0[4*j+3] * c.w;
            c0 += v1[4*j+0] * c.x; c1 += v1[4*j+1] * c.y;
            c2 += v1[4*j+2] * c.z; c3 += v1[4*j+3] * c.w;
        }
        float s0 = (a0 + a1) + (a2 + a3) - lhn[k];
        float s1 = (c0 + c1) + (c2 + c3) - lhn[k];
        if (s0 > best0) { best0 = s0; k0 = k; }
        if (s1 > best1) { best1 = s1; k1 = k; }
    }

    float rinv0 = 1.f / (sqrtf(fmaxf(q0 - 2.f * best0, 0.f)) + 1e-8f);
    kout[p0] = (unsigned char)k0;
    rinvout[p0] = rinv0;
    if (w1) {
        float rinv1 = 1.f / (sqrtf(fmaxf(q1 - 2.f * best1, 0.f)) + 1e-8f);
        kout[p1] = (unsigned char)k1;
        rinvout[p1] = rinv1;
    }
}

// ------------------------------------------- per-batch aggregation + standardize
// One block per batch. acc[k][d] = sum(vw*rinv); S[k] = sum(rinv);
// vlad[k][d] = acc - codes[k][d]*S[k]; then mean/std(ddof=1) fused.
#define APAD 65   // bank = (65k + d) % 32 = (k + d) % 32 -> random-k lanes spread
__global__ __launch_bounds__(1024) void aggregate_kernel(const float* __restrict__ feat,
                                                         const float* __restrict__ codes,
                                                         const float* __restrict__ inv_norm,
                                                         const unsigned char* __restrict__ kout,
                                                         const float* __restrict__ rinvout,
                                                         float* __restrict__ out) {
    __shared__ float acc[KC * APAD];   // 64480 B
    __shared__ float S[KC];
    __shared__ float inv_l[D_];
    __shared__ double rs[1024], rss[1024];

    int b = blockIdx.x, t = threadIdx.x;
    for (int i = t; i < KC * APAD; i += 1024) acc[i] = 0.f;
    for (int i = t; i < KC; i += 1024) S[i] = 0.f;
    if (t < D_) inv_l[t] = inv_norm[b * D_ + t];
    __syncthreads();

    for (int p0 = t; p0 < NPB; p0 += 1024) {
        int p = b * NPB + p0;
        int k = (int)kout[p];
        float rv = rinvout[p];
        const float4* f = (const float4*)(feat + (size_t)p * D_);
        float* a = acc + k * APAD;
        #pragma unroll
        for (int j = 0; j < 16; ++j) {
            float4 x = f[j];
            float4 w = *(const float4*)(inv_l + 4 * j);
            atomicAdd(a + 4*j + 0, x.x * w.x * rv);
            atomicAdd(a + 4*j + 1, x.y * w.y * rv);
            atomicAdd(a + 4*j + 2, x.z * w.z * rv);
            atomicAdd(a + 4*j + 3, x.w * w.w * rv);
        }
        atomicAdd(&S[k], rv);
    }
    __syncthreads();

    // finalize: val = acc - codes*S, accumulate mean/var sums, stash val in acc
    double s = 0.0, ss = 0.0;
    for (int i = t; i < NV; i += 1024) {
        int k = i >> 6, d = i & 63;
        float val = acc[k * APAD + d] - codes[i] * S[k];
        acc[k * APAD + d] = val;
        s += (double)val;
        ss += (double)val * (double)val;
    }
    rs[t] = s; rss[t] = ss;
    __syncthreads();
    for (int off = 512; off > 0; off >>= 1) {
        if (t < off) { rs[t] += rs[t + off]; rss[t] += rss[t + off]; }
        __syncthreads();
    }
    __shared__ float fmean, fscale;
    if (t == 0) {
        double Sm = rs[0], SSm = rss[0];
        double mean = Sm / (double)NV;
        double var = (SSm - Sm * Sm / (double)NV) / (double)(NV - 1);
        double sd = sqrt(var > 0.0 ? var : 0.0);
        fmean = (float)mean;
        fscale = (float)(1.0 / (sd + 1e-8));
    }
    __syncthreads();
    float m = fmean, sc = fscale;
    float* row = out + (size_t)b * NV;
    for (int i = t; i < NV; i += 1024) {
        int k = i >> 6, d = i & 63;
        row[i] = (acc[k * APAD + d] - m) * sc;
    }
}

extern "C" void kernel_launch(void* const* d_in, const int* in_sizes, int n_in,
                              void* d_out, int out_size, void* d_ws, size_t ws_size,
                              hipStream_t stream) {
    const float* feat  = (const float*)d_in[0];
    const float* codes = (const float*)d_in[1];
    float* out = (float*)d_out;

    float* inv_norm = (float*)d_ws;                  // 4096 floats
    float* hn       = inv_norm + B_ * D_;            // 248 floats
    float* rinvbuf  = hn + KC;                       // 221952 floats
    unsigned char* kbuf = (unsigned char*)(rinvbuf + NPTS);  // 221952 bytes

    hipLaunchKernelGGL(norms_kernel, dim3(B_ + 1), dim3(256), 0, stream,
                       feat, codes, inv_norm, hn);
    hipLaunchKernelGGL(assign_kernel, dim3((NPTS + 511) / 512), dim3(256), 0, stream,
                       feat, codes, inv_norm, hn, kbuf, rinvbuf);
    hipLaunchKernelGGL(aggregate_kernel, dim3(B_), dim3(1024), 0, stream,
                       feat, codes, inv_norm, kbuf, rinvbuf, out);
}